// Round 1
// baseline (347.655 us; speedup 1.0000x reference)
//
#include <hip/hip_runtime.h>
#include <stdint.h>

// Global: forbid FMA contraction so float32 results mirror XLA-CPU's
// non-contracted elementwise arithmetic (iou>=0.5 and round(0.5) boundaries).
#pragma clang fp contract(off)

#define NB 16
#define NPROP 2000
#define MAXGT 100
#define NUMPOS 66
#define NUMNEG 134
#define NROIS 200
#define IMH 160
#define IMW 160
#define MHH 28
#define MWW 28
#define BLK 256

#define ROIS_OFF 0
#define CLS_OFF (NB * NROIS * 4)               /* 12800 */
#define DELTA_OFF (CLS_OFF + NB * NROIS)       /* 16000 */
#define MASK_OFF (DELTA_OFF + NB * NROIS * 4)  /* 28800 */

__device__ __forceinline__ unsigned rotl32(unsigned v, int d) {
  return (v << d) | (v >> (32 - d));
}

// JAX threefry2x32 (jax/_src/prng.py), 20 rounds, key schedule +1..+5.
__device__ void threefry2x32(unsigned k0, unsigned k1, unsigned c0, unsigned c1,
                             unsigned &o0, unsigned &o1) {
  const unsigned ks2 = k0 ^ k1 ^ 0x1BD11BDAu;
  unsigned x0 = c0 + k0;
  unsigned x1 = c1 + k1;
  const int rA[4] = {13, 15, 26, 6};
  const int rB[4] = {17, 29, 16, 24};
#pragma unroll
  for (int i = 0; i < 4; i++) { x0 += x1; x1 = rotl32(x1, rA[i]); x1 ^= x0; }
  x0 += k1;  x1 += ks2 + 1u;
#pragma unroll
  for (int i = 0; i < 4; i++) { x0 += x1; x1 = rotl32(x1, rB[i]); x1 ^= x0; }
  x0 += ks2; x1 += k0 + 2u;
#pragma unroll
  for (int i = 0; i < 4; i++) { x0 += x1; x1 = rotl32(x1, rA[i]); x1 ^= x0; }
  x0 += k0;  x1 += k1 + 3u;
#pragma unroll
  for (int i = 0; i < 4; i++) { x0 += x1; x1 = rotl32(x1, rB[i]); x1 ^= x0; }
  x0 += k1;  x1 += ks2 + 4u;
#pragma unroll
  for (int i = 0; i < 4; i++) { x0 += x1; x1 = rotl32(x1, rA[i]); x1 ^= x0; }
  x0 += ks2; x1 += k0 + 5u;
  o0 = x0; o1 = x1;
}

// Partitionable random_bits (32-bit): bits[i] = xor of both output words of
// threefry(key, (hi64(i)=0, lo64(i)=i)); uniform = bitcast trick - 1.0.
__device__ __forceinline__ float tf_uniform01(unsigned k0, unsigned k1,
                                              unsigned i) {
  unsigned a, b;
  threefry2x32(k0, k1, 0u, i, a, b);
  unsigned bits = a ^ b;
  return __uint_as_float((bits >> 9) | 0x3f800000u) - 1.0f;
}

// Stable top-K (lax.top_k semantics) of sc[0..NPROP) where candidates have
// sc >= 0 (non-candidates are -1).  Histogram -> threshold bin -> compact
// contenders -> all-pairs rank.  slot arrays get index/score per rank; -1 for
// unfilled slots.
__device__ void select_topk(const float* sc, int K, int* hist, int* cand_i,
                            float* cand_s, int* slot_i, float* slot_s,
                            int* misc) {
  const int tid = threadIdx.x;
  for (int v = tid; v < 256; v += BLK) hist[v] = 0;
  if (tid == 0) misc[0] = 0;
  __syncthreads();
  for (int i = tid; i < NPROP; i += BLK) {
    float s = sc[i];
    if (s >= 0.0f) {
      int bin = (int)(s * 256.0f); if (bin > 255) bin = 255;
      atomicAdd(&hist[bin], 1);
    }
  }
  __syncthreads();
  if (tid == 0) {
    int acc = 0, T = 0;
    for (int v = 255; v >= 0; --v) {
      acc += hist[v];
      if (acc >= K) { T = v; break; }
    }
    misc[1] = T;
  }
  __syncthreads();
  const int T = misc[1];
  for (int i = tid; i < NPROP; i += BLK) {
    float s = sc[i];
    if (s >= 0.0f) {
      int bin = (int)(s * 256.0f); if (bin > 255) bin = 255;
      if (bin >= T) {
        int t = atomicAdd(&misc[0], 1);
        cand_i[t] = i; cand_s[t] = s;
      }
    }
  }
  for (int j = tid; j < K; j += BLK) { slot_i[j] = -1; slot_s[j] = -1.0f; }
  __syncthreads();
  const int C = misc[0];
  for (int t = tid; t < C; t += BLK) {
    float st = cand_s[t]; int it = cand_i[t];
    int r = 0;
    for (int u = 0; u < C; ++u) {
      float su = cand_s[u];
      r += (su > st) || (su == st && cand_i[u] < it);
    }
    if (r < K) { slot_i[r] = it; slot_s[r] = st; }
  }
  __syncthreads();
}

__global__ __launch_bounds__(BLK) void dtl_select_kernel(
    const float* __restrict__ proposals,   // [NB,NPROP,4]
    const int* __restrict__ gt_class,      // [NB,MAXGT]
    const float* __restrict__ gt_boxes,    // [NB,MAXGT,4]
    const float* __restrict__ std_dev,     // [4]
    float* __restrict__ out,
    int* __restrict__ ws_slots) {          // [NB,NUMPOS,2] (pidx or -1, gt arg)
#pragma clang fp contract(off)
  const int b = blockIdx.x;
  const int tid = threadIdx.x;

  __shared__ float s_gt[MAXGT][4];
  __shared__ int s_gtvalid[MAXGT];
  __shared__ int s_gtcls[MAXGT];
  __shared__ float s_poss[NPROP];
  __shared__ float s_negs[NPROP];
  __shared__ unsigned char s_arg[NPROP];
  __shared__ int s_hist[256];
  __shared__ int s_cand_i[NPROP];
  __shared__ float s_cand_s[NPROP];
  __shared__ int s_pslot_i[NUMPOS];
  __shared__ float s_pslot_s[NUMPOS];
  __shared__ int s_nslot_i[NUMNEG];
  __shared__ float s_nslot_s[NUMNEG];
  __shared__ int s_misc[4];  // 0: compact count, 1: thresh bin, 2: P, 3: neg_needed

  for (int g = tid; g < MAXGT; g += BLK) {
    int cls = gt_class[b * MAXGT + g];
    s_gtcls[g] = cls;
    s_gtvalid[g] = (cls > 0) ? 1 : 0;
    s_gt[g][0] = gt_boxes[(b * MAXGT + g) * 4 + 0];
    s_gt[g][1] = gt_boxes[(b * MAXGT + g) * 4 + 1];
    s_gt[g][2] = gt_boxes[(b * MAXGT + g) * 4 + 2];
    s_gt[g][3] = gt_boxes[(b * MAXGT + g) * 4 + 3];
  }
  __syncthreads();

  // key chain: root=(0,42); keys[b]=tf(root,0,b); kp=tf(kb,0,0); kn=tf(kb,0,1)
  unsigned kb0, kb1, kp0, kp1, kn0, kn1;
  threefry2x32(0u, 42u, 0u, (unsigned)b, kb0, kb1);
  threefry2x32(kb0, kb1, 0u, 0u, kp0, kp1);
  threefry2x32(kb0, kb1, 0u, 1u, kn0, kn1);

  for (int i = tid; i < NPROP; i += BLK) {
    float p0 = proposals[(b * NPROP + i) * 4 + 0];
    float p1 = proposals[(b * NPROP + i) * 4 + 1];
    float p2 = proposals[(b * NPROP + i) * 4 + 2];
    float p3 = proposals[(b * NPROP + i) * 4 + 3];
    bool vp = (p0 != 0.0f) || (p1 != 0.0f) || (p2 != 0.0f) || (p3 != 0.0f);
    float a1 = (p2 - p0) * (p3 - p1);
    float best = -2.0f;
    int arg = 0;
    for (int g = 0; g < MAXGT; ++g) {
      float g0 = s_gt[g][0], g1 = s_gt[g][1], g2 = s_gt[g][2], g3 = s_gt[g][3];
      float yA = fmaxf(p0, g0);
      float xA = fmaxf(p1, g1);
      float yB = fminf(p2, g2);
      float xB = fminf(p3, g3);
      float inter = fmaxf(yB - yA, 0.0f) * fmaxf(xB - xA, 0.0f);
      float a2 = (g2 - g0) * (g3 - g1);
      float uni = (a1 + a2) - inter;
      float iou = inter / fmaxf(uni, 1e-10f);
      float v = s_gtvalid[g] ? iou : -1.0f;
      if (v > best) { best = v; arg = g; }  // strict > : first-occurrence argmax
    }
    bool pos = (best >= 0.5f) && vp;
    bool neg = (best < 0.5f) && vp;
    s_poss[i] = pos ? tf_uniform01(kp0, kp1, (unsigned)i) : -1.0f;
    s_negs[i] = neg ? tf_uniform01(kn0, kn1, (unsigned)i) : -1.0f;
    s_arg[i] = (unsigned char)arg;
  }
  __syncthreads();

  select_topk(s_poss, NUMPOS, s_hist, s_cand_i, s_cand_s, s_pslot_i, s_pslot_s,
              s_misc);

  if (tid == 0) {
    int P = 0;
    for (int j = 0; j < NUMPOS; ++j) P += (s_pslot_s[j] > 0.0f) ? 1 : 0;
    int t = (int)((float)P / 0.33f);  // float32 div + trunc, as in reference
    int nn = t - P;
    nn = nn < 0 ? 0 : nn;
    nn = nn > NUMNEG ? NUMNEG : nn;
    s_misc[2] = P;
    s_misc[3] = nn;
  }
  __syncthreads();
  const int neg_needed = s_misc[3];

  select_topk(s_negs, NUMNEG, s_hist, s_cand_i, s_cand_s, s_nslot_i, s_nslot_s,
              s_misc);

  const float sd0 = std_dev[0], sd1 = std_dev[1], sd2 = std_dev[2],
              sd3 = std_dev[3];

  for (int j = tid; j < NROIS; j += BLK) {
    float r0 = 0, r1 = 0, r2 = 0, r3 = 0;
    float d0 = 0, d1 = 0, d2 = 0, d3 = 0;
    float cls = 0;
    if (j < NUMPOS) {
      int idx = s_pslot_i[j];
      bool valid = (idx >= 0) && (s_pslot_s[j] > 0.0f);
      int g = 0;
      if (valid) {
        const float* p = proposals + (size_t)(b * NPROP + idx) * 4;
        r0 = p[0]; r1 = p[1]; r2 = p[2]; r3 = p[3];
        g = (int)s_arg[idx];
        float g0 = s_gt[g][0], g1 = s_gt[g][1], g2 = s_gt[g][2], g3 = s_gt[g][3];
        float h = r2 - r0, w = r3 - r1;
        float cy = r0 + 0.5f * h, cx = r1 + 0.5f * w;
        float gh = g2 - g0, gw = g3 - g1;
        float gcy = g0 + 0.5f * gh, gcx = g1 + 0.5f * gw;
        d0 = ((gcy - cy) / h) / sd0;
        d1 = ((gcx - cx) / w) / sd1;
        d2 = logf(gh / h) / sd2;
        d3 = logf(gw / w) / sd3;
        cls = (float)s_gtcls[g];
      }
      ws_slots[(b * NUMPOS + j) * 2 + 0] = valid ? idx : -1;
      ws_slots[(b * NUMPOS + j) * 2 + 1] = g;
    } else {
      int jn = j - NUMPOS;
      int idx = s_nslot_i[jn];
      bool valid = (idx >= 0) && (s_nslot_s[jn] > 0.0f) && (jn < neg_needed);
      if (valid) {
        const float* p = proposals + (size_t)(b * NPROP + idx) * 4;
        r0 = p[0]; r1 = p[1]; r2 = p[2]; r3 = p[3];
      }
    }
    out[ROIS_OFF + (b * NROIS + j) * 4 + 0] = r0;
    out[ROIS_OFF + (b * NROIS + j) * 4 + 1] = r1;
    out[ROIS_OFF + (b * NROIS + j) * 4 + 2] = r2;
    out[ROIS_OFF + (b * NROIS + j) * 4 + 3] = r3;
    out[CLS_OFF + b * NROIS + j] = cls;
    out[DELTA_OFF + (b * NROIS + j) * 4 + 0] = d0;
    out[DELTA_OFF + (b * NROIS + j) * 4 + 1] = d1;
    out[DELTA_OFF + (b * NROIS + j) * 4 + 2] = d2;
    out[DELTA_OFF + (b * NROIS + j) * 4 + 3] = d3;
  }
}

__global__ __launch_bounds__(256) void dtl_mask_kernel(
    const float* __restrict__ proposals,  // [NB,NPROP,4]
    const float* __restrict__ gmasks,     // [NB,IMH,IMW,MAXGT]
    const int* __restrict__ ws_slots,     // [NB,NUMPOS,2]
    float* __restrict__ out) {
#pragma clang fp contract(off)
  const int bs = blockIdx.x;
  const int b = bs / NROIS;
  const int slot = bs % NROIS;
  float* mo = out + MASK_OFF + (size_t)(b * NROIS + slot) * (MHH * MWW);
  int pidx = -1, g = 0;
  if (slot < NUMPOS) {
    pidx = ws_slots[(b * NUMPOS + slot) * 2 + 0];
    g = ws_slots[(b * NUMPOS + slot) * 2 + 1];
  }
  if (pidx < 0) {
    for (int p = threadIdx.x; p < MHH * MWW; p += 256) mo[p] = 0.0f;
    return;
  }
  const float* bx = proposals + (size_t)(b * NPROP + pidx) * 4;
  const float y1 = bx[0], x1 = bx[1], y2 = bx[2], x2 = bx[3];
  const float* img = gmasks + (size_t)b * IMH * IMW * MAXGT + g;
  for (int p = threadIdx.x; p < MHH * MWW; p += 256) {
    int m = p / MWW, n = p % MWW;
    float ty = (float)m / (float)(MHH - 1);
    float tx = (float)n / (float)(MWW - 1);
    float ys = (y1 + ty * (y2 - y1)) * (float)(IMH - 1);
    float xs = (x1 + tx * (x2 - x1)) * (float)(IMW - 1);
    float y0f = floorf(ys), x0f = floorf(xs);
    float fy = ys - y0f, fx = xs - x0f;
    int y0 = (int)y0f; y0 = y0 < 0 ? 0 : (y0 > IMH - 1 ? IMH - 1 : y0);
    int y1i = y0 + 1;  y1i = y1i > IMH - 1 ? IMH - 1 : y1i;
    int x0 = (int)x0f; x0 = x0 < 0 ? 0 : (x0 > IMW - 1 ? IMW - 1 : x0);
    int x1i = x0 + 1;  x1i = x1i > IMW - 1 ? IMW - 1 : x1i;
    float m00 = img[((size_t)y0 * IMW + x0) * MAXGT];
    float m01 = img[((size_t)y0 * IMW + x1i) * MAXGT];
    float m10 = img[((size_t)y1i * IMW + x0) * MAXGT];
    float m11 = img[((size_t)y1i * IMW + x1i) * MAXGT];
    float v = m00 * (1.0f - fy) * (1.0f - fx)
            + m01 * (1.0f - fy) * fx
            + m10 * fy * (1.0f - fx)
            + m11 * fy * fx;
    mo[p] = rintf(v);  // jnp.round: half-to-even; * pos_valid(==1) implicit
  }
}

extern "C" void kernel_launch(void* const* d_in, const int* in_sizes, int n_in,
                              void* d_out, int out_size, void* d_ws,
                              size_t ws_size, hipStream_t stream) {
  const float* proposals = (const float*)d_in[0];
  const int* gt_class = (const int*)d_in[1];
  const float* gt_boxes = (const float*)d_in[2];
  const float* gmasks = (const float*)d_in[3];
  const float* std_dev = (const float*)d_in[4];
  float* out = (float*)d_out;
  int* ws_slots = (int*)d_ws;  // NB*NUMPOS*2 ints = 8448 B

  dtl_select_kernel<<<NB, BLK, 0, stream>>>(proposals, gt_class, gt_boxes,
                                            std_dev, out, ws_slots);
  dtl_mask_kernel<<<NB * NROIS, 256, 0, stream>>>(proposals, gmasks, ws_slots,
                                                  out);
}

// Round 2
// 271.769 us; speedup vs baseline: 1.2792x; 1.2792x over previous
//
#include <hip/hip_runtime.h>
#include <stdint.h>

// Forbid FMA contraction so float32 results mirror XLA-CPU's non-contracted
// elementwise arithmetic (iou>=0.5 and round(0.5) boundaries).
#pragma clang fp contract(off)

#define NB 16
#define NPROP 2000
#define MAXGT 100
#define NUMPOS 66
#define NUMNEG 134
#define NROIS 200
#define IMH 160
#define IMW 160
#define MHH 28
#define MWW 28
#define BLK 256

#define ROIS_OFF 0
#define CLS_OFF (NB * NROIS * 4)               /* 12800 */
#define DELTA_OFF (CLS_OFF + NB * NROIS)       /* 16000 */
#define MASK_OFF (DELTA_OFF + NB * NROIS * 4)  /* 28800 */

__device__ __forceinline__ unsigned rotl32(unsigned v, int d) {
  return (v << d) | (v >> (32 - d));
}

// JAX threefry2x32 (jax/_src/prng.py), 20 rounds, key schedule +1..+5.
__device__ void threefry2x32(unsigned k0, unsigned k1, unsigned c0, unsigned c1,
                             unsigned &o0, unsigned &o1) {
  const unsigned ks2 = k0 ^ k1 ^ 0x1BD11BDAu;
  unsigned x0 = c0 + k0;
  unsigned x1 = c1 + k1;
  const int rA[4] = {13, 15, 26, 6};
  const int rB[4] = {17, 29, 16, 24};
#pragma unroll
  for (int i = 0; i < 4; i++) { x0 += x1; x1 = rotl32(x1, rA[i]); x1 ^= x0; }
  x0 += k1;  x1 += ks2 + 1u;
#pragma unroll
  for (int i = 0; i < 4; i++) { x0 += x1; x1 = rotl32(x1, rB[i]); x1 ^= x0; }
  x0 += ks2; x1 += k0 + 2u;
#pragma unroll
  for (int i = 0; i < 4; i++) { x0 += x1; x1 = rotl32(x1, rA[i]); x1 ^= x0; }
  x0 += k0;  x1 += k1 + 3u;
#pragma unroll
  for (int i = 0; i < 4; i++) { x0 += x1; x1 = rotl32(x1, rB[i]); x1 ^= x0; }
  x0 += k1;  x1 += ks2 + 4u;
#pragma unroll
  for (int i = 0; i < 4; i++) { x0 += x1; x1 = rotl32(x1, rA[i]); x1 ^= x0; }
  x0 += ks2; x1 += k0 + 5u;
  o0 = x0; o1 = x1;
}

// Partitionable random_bits (32-bit): bits[i] = xor of the two output words of
// threefry(key, (0, i)); uniform = bitcast((bits>>9)|0x3f800000) - 1.
__device__ __forceinline__ float tf_uniform01(unsigned k0, unsigned k1,
                                              unsigned i) {
  unsigned a, b;
  threefry2x32(k0, k1, 0u, i, a, b);
  unsigned bits = a ^ b;
  return __uint_as_float((bits >> 9) | 0x3f800000u) - 1.0f;
}

// ---------------------------------------------------------------------------
// Kernel 1: per-proposal scoring. grid (8, NB) x 256 threads, one thread per
// proposal: IoU argmax over 100 GT (LDS), threefry uniform for the branch the
// proposal falls in. Writes pos/neg score arrays + argmax to ws.
// ---------------------------------------------------------------------------
__global__ __launch_bounds__(BLK) void dtl_score_kernel(
    const float* __restrict__ proposals,   // [NB,NPROP,4]
    const int* __restrict__ gt_class,      // [NB,MAXGT]
    const float* __restrict__ gt_boxes,    // [NB,MAXGT,4]
    float* __restrict__ ws_pos_s,          // [NB,NPROP]
    float* __restrict__ ws_neg_s,          // [NB,NPROP]
    unsigned char* __restrict__ ws_arg) {  // [NB,NPROP]
#pragma clang fp contract(off)
  const int b = blockIdx.y;
  const int i = blockIdx.x * BLK + threadIdx.x;

  __shared__ float s_gt[MAXGT][4];
  __shared__ float s_area[MAXGT];
  __shared__ int s_gtvalid[MAXGT];
  for (int g = threadIdx.x; g < MAXGT; g += BLK) {
    s_gtvalid[g] = (gt_class[b * MAXGT + g] > 0) ? 1 : 0;
    float g0 = gt_boxes[(b * MAXGT + g) * 4 + 0];
    float g1 = gt_boxes[(b * MAXGT + g) * 4 + 1];
    float g2 = gt_boxes[(b * MAXGT + g) * 4 + 2];
    float g3 = gt_boxes[(b * MAXGT + g) * 4 + 3];
    s_gt[g][0] = g0; s_gt[g][1] = g1; s_gt[g][2] = g2; s_gt[g][3] = g3;
    s_area[g] = (g2 - g0) * (g3 - g1);
  }
  __syncthreads();
  if (i >= NPROP) return;

  float p0 = proposals[(b * NPROP + i) * 4 + 0];
  float p1 = proposals[(b * NPROP + i) * 4 + 1];
  float p2 = proposals[(b * NPROP + i) * 4 + 2];
  float p3 = proposals[(b * NPROP + i) * 4 + 3];
  bool vp = (p0 != 0.0f) || (p1 != 0.0f) || (p2 != 0.0f) || (p3 != 0.0f);
  float a1 = (p2 - p0) * (p3 - p1);
  float best = -2.0f;
  int arg = 0;
  for (int g = 0; g < MAXGT; ++g) {
    float yA = fmaxf(p0, s_gt[g][0]);
    float xA = fmaxf(p1, s_gt[g][1]);
    float yB = fminf(p2, s_gt[g][2]);
    float xB = fminf(p3, s_gt[g][3]);
    float inter = fmaxf(yB - yA, 0.0f) * fmaxf(xB - xA, 0.0f);
    float uni = (a1 + s_area[g]) - inter;
    float iou = inter / fmaxf(uni, 1e-10f);
    float v = s_gtvalid[g] ? iou : -1.0f;
    if (v > best) { best = v; arg = g; }  // strict > : first-occurrence argmax
  }

  float pos_s = -1.0f, neg_s = -1.0f;
  if (vp) {
    // key chain: root=(0,42); kb=tf(root,0,b); kp=tf(kb,0,0); kn=tf(kb,0,1)
    unsigned kb0, kb1, k0, k1;
    threefry2x32(0u, 42u, 0u, (unsigned)b, kb0, kb1);
    bool pos = (best >= 0.5f);
    threefry2x32(kb0, kb1, 0u, pos ? 0u : 1u, k0, k1);
    float u = tf_uniform01(k0, k1, (unsigned)i);
    if (pos) pos_s = u; else neg_s = u;
  }
  ws_pos_s[b * NPROP + i] = pos_s;
  ws_neg_s[b * NPROP + i] = neg_s;
  ws_arg[b * NPROP + i] = (unsigned char)arg;
}

// ---------------------------------------------------------------------------
// Kernel 2: per-(image, pos/neg) stable top-K + output writing.
// grid NB*2 x 256. Histogram -> parallel suffix scan (Hillis-Steele, 8 steps)
// -> threshold bin -> compact -> all-pairs stable rank (lax.top_k semantics:
// score desc, index asc). pos block writes rois/cls/deltas[0..65] + ws_slots;
// neg block recomputes P from ws_pos_s and writes rois/cls/deltas[66..199].
// ---------------------------------------------------------------------------
__global__ __launch_bounds__(BLK) void dtl_topk_kernel(
    const float* __restrict__ proposals,
    const int* __restrict__ gt_class,
    const float* __restrict__ gt_boxes,
    const float* __restrict__ std_dev,
    const float* __restrict__ ws_pos_s,
    const float* __restrict__ ws_neg_s,
    const unsigned char* __restrict__ ws_arg,
    float* __restrict__ out,
    int* __restrict__ ws_slots) {
#pragma clang fp contract(off)
  const int b = blockIdx.x >> 1;
  const bool is_pos = (blockIdx.x & 1) == 0;
  const int K = is_pos ? NUMPOS : NUMNEG;
  const int tid = threadIdx.x;

  __shared__ float s_sc[NPROP];
  __shared__ int s_hist[256];
  __shared__ int s_cand_i[NPROP];
  __shared__ float s_cand_s[NPROP];
  __shared__ int s_slot_i[NUMNEG];
  __shared__ float s_slot_s[NUMNEG];
  __shared__ float s_gt[MAXGT][4];
  __shared__ int s_gtcls[MAXGT];
  __shared__ int s_misc[4];  // 0: compact count, 1: T, 2: pos count

  const float* sc_g = (is_pos ? ws_pos_s : ws_neg_s) + (size_t)b * NPROP;
  for (int i = tid; i < NPROP; i += BLK) s_sc[i] = sc_g[i];
  for (int g = tid; g < MAXGT; g += BLK) {
    s_gtcls[g] = gt_class[b * MAXGT + g];
    s_gt[g][0] = gt_boxes[(b * MAXGT + g) * 4 + 0];
    s_gt[g][1] = gt_boxes[(b * MAXGT + g) * 4 + 1];
    s_gt[g][2] = gt_boxes[(b * MAXGT + g) * 4 + 2];
    s_gt[g][3] = gt_boxes[(b * MAXGT + g) * 4 + 3];
  }
  s_hist[tid] = 0;
  if (tid < 4) s_misc[tid] = 0;
  __syncthreads();

  // histogram (256 bins over [0,1))
  for (int i = tid; i < NPROP; i += BLK) {
    float s = s_sc[i];
    if (s >= 0.0f) {
      int bin = (int)(s * 256.0f); if (bin > 255) bin = 255;
      atomicAdd(&s_hist[bin], 1);
    }
  }
  __syncthreads();

  // parallel suffix sum: s_hist[v] := sum_{u>=v} hist[u]
  for (int d = 1; d < 256; d <<= 1) {
    int add = (tid + d < 256) ? s_hist[tid + d] : 0;
    __syncthreads();
    s_hist[tid] += add;
    __syncthreads();
  }
  // T = max v with suffix[v] >= K (0 if none)
  {
    int sv = s_hist[tid];
    int svn = (tid < 255) ? s_hist[tid + 1] : 0;
    if (sv >= K && (tid == 255 || svn < K)) s_misc[1] = tid;
  }
  __syncthreads();
  const int T = s_misc[1];

  // compact candidates in bins >= T
  for (int i = tid; i < NPROP; i += BLK) {
    float s = s_sc[i];
    if (s >= 0.0f) {
      int bin = (int)(s * 256.0f); if (bin > 255) bin = 255;
      if (bin >= T) {
        int t = atomicAdd(&s_misc[0], 1);
        s_cand_i[t] = i; s_cand_s[t] = s;
      }
    }
  }
  for (int j = tid; j < K; j += BLK) { s_slot_i[j] = -1; s_slot_s[j] = -1.0f; }
  __syncthreads();

  // all-pairs stable rank
  const int C = s_misc[0];
  for (int t = tid; t < C; t += BLK) {
    float st = s_cand_s[t]; int it = s_cand_i[t];
    int r = 0;
    for (int u = 0; u < C; ++u) {
      float su = s_cand_s[u];
      r += (su > st) || (su == st && s_cand_i[u] < it);
    }
    if (r < K) { s_slot_i[r] = it; s_slot_s[r] = st; }
  }
  __syncthreads();

  if (is_pos) {
    const float sd0 = std_dev[0], sd1 = std_dev[1], sd2 = std_dev[2],
                sd3 = std_dev[3];
    for (int j = tid; j < NUMPOS; j += BLK) {
      float r0 = 0, r1 = 0, r2 = 0, r3 = 0;
      float d0 = 0, d1 = 0, d2 = 0, d3 = 0;
      float cls = 0;
      int idx = s_slot_i[j];
      bool valid = (idx >= 0) && (s_slot_s[j] > 0.0f);
      int g = 0;
      if (valid) {
        const float* p = proposals + (size_t)(b * NPROP + idx) * 4;
        r0 = p[0]; r1 = p[1]; r2 = p[2]; r3 = p[3];
        g = (int)ws_arg[(size_t)b * NPROP + idx];
        float g0 = s_gt[g][0], g1 = s_gt[g][1], g2 = s_gt[g][2],
              g3 = s_gt[g][3];
        float h = r2 - r0, w = r3 - r1;
        float cy = r0 + 0.5f * h, cx = r1 + 0.5f * w;
        float gh = g2 - g0, gw = g3 - g1;
        float gcy = g0 + 0.5f * gh, gcx = g1 + 0.5f * gw;
        d0 = ((gcy - cy) / h) / sd0;
        d1 = ((gcx - cx) / w) / sd1;
        d2 = logf(gh / h) / sd2;
        d3 = logf(gw / w) / sd3;
        cls = (float)s_gtcls[g];
      }
      ws_slots[(b * NUMPOS + j) * 2 + 0] = valid ? idx : -1;
      ws_slots[(b * NUMPOS + j) * 2 + 1] = g;
      out[ROIS_OFF + (b * NROIS + j) * 4 + 0] = r0;
      out[ROIS_OFF + (b * NROIS + j) * 4 + 1] = r1;
      out[ROIS_OFF + (b * NROIS + j) * 4 + 2] = r2;
      out[ROIS_OFF + (b * NROIS + j) * 4 + 3] = r3;
      out[CLS_OFF + b * NROIS + j] = cls;
      out[DELTA_OFF + (b * NROIS + j) * 4 + 0] = d0;
      out[DELTA_OFF + (b * NROIS + j) * 4 + 1] = d1;
      out[DELTA_OFF + (b * NROIS + j) * 4 + 2] = d2;
      out[DELTA_OFF + (b * NROIS + j) * 4 + 3] = d3;
    }
  } else {
    // P = min(#{pos_s > 0}, NUMPOS); neg_needed = trunc(P/0.33f) - P, clipped
    {
      int cnt = 0;
      const float* ps = ws_pos_s + (size_t)b * NPROP;
      for (int i = tid; i < NPROP; i += BLK) cnt += (ps[i] > 0.0f) ? 1 : 0;
      atomicAdd(&s_misc[2], cnt);
    }
    __syncthreads();
    int P = s_misc[2]; P = P > NUMPOS ? NUMPOS : P;
    int t = (int)((float)P / 0.33f);  // float32 div + trunc, as in reference
    int neg_needed = t - P;
    neg_needed = neg_needed < 0 ? 0 : neg_needed;
    neg_needed = neg_needed > NUMNEG ? NUMNEG : neg_needed;

    for (int jn = tid; jn < NUMNEG; jn += BLK) {
      int j = NUMPOS + jn;
      float r0 = 0, r1 = 0, r2 = 0, r3 = 0;
      int idx = s_slot_i[jn];
      bool valid = (idx >= 0) && (s_slot_s[jn] > 0.0f) && (jn < neg_needed);
      if (valid) {
        const float* p = proposals + (size_t)(b * NPROP + idx) * 4;
        r0 = p[0]; r1 = p[1]; r2 = p[2]; r3 = p[3];
      }
      out[ROIS_OFF + (b * NROIS + j) * 4 + 0] = r0;
      out[ROIS_OFF + (b * NROIS + j) * 4 + 1] = r1;
      out[ROIS_OFF + (b * NROIS + j) * 4 + 2] = r2;
      out[ROIS_OFF + (b * NROIS + j) * 4 + 3] = r3;
      out[CLS_OFF + b * NROIS + j] = 0.0f;
      out[DELTA_OFF + (b * NROIS + j) * 4 + 0] = 0.0f;
      out[DELTA_OFF + (b * NROIS + j) * 4 + 1] = 0.0f;
      out[DELTA_OFF + (b * NROIS + j) * 4 + 2] = 0.0f;
      out[DELTA_OFF + (b * NROIS + j) * 4 + 3] = 0.0f;
    }
  }
}

// ---------------------------------------------------------------------------
// Kernel 3: mask crop_and_resize (unchanged from passing round 1).
// ---------------------------------------------------------------------------
__global__ __launch_bounds__(256) void dtl_mask_kernel(
    const float* __restrict__ proposals,  // [NB,NPROP,4]
    const float* __restrict__ gmasks,     // [NB,IMH,IMW,MAXGT]
    const int* __restrict__ ws_slots,     // [NB,NUMPOS,2]
    float* __restrict__ out) {
#pragma clang fp contract(off)
  const int bs = blockIdx.x;
  const int b = bs / NROIS;
  const int slot = bs % NROIS;
  float* mo = out + MASK_OFF + (size_t)(b * NROIS + slot) * (MHH * MWW);
  int pidx = -1, g = 0;
  if (slot < NUMPOS) {
    pidx = ws_slots[(b * NUMPOS + slot) * 2 + 0];
    g = ws_slots[(b * NUMPOS + slot) * 2 + 1];
  }
  if (pidx < 0) {
    for (int p = threadIdx.x; p < MHH * MWW; p += 256) mo[p] = 0.0f;
    return;
  }
  const float* bx = proposals + (size_t)(b * NPROP + pidx) * 4;
  const float y1 = bx[0], x1 = bx[1], y2 = bx[2], x2 = bx[3];
  const float* img = gmasks + (size_t)b * IMH * IMW * MAXGT + g;
  for (int p = threadIdx.x; p < MHH * MWW; p += 256) {
    int m = p / MWW, n = p % MWW;
    float ty = (float)m / (float)(MHH - 1);
    float tx = (float)n / (float)(MWW - 1);
    float ys = (y1 + ty * (y2 - y1)) * (float)(IMH - 1);
    float xs = (x1 + tx * (x2 - x1)) * (float)(IMW - 1);
    float y0f = floorf(ys), x0f = floorf(xs);
    float fy = ys - y0f, fx = xs - x0f;
    int y0 = (int)y0f; y0 = y0 < 0 ? 0 : (y0 > IMH - 1 ? IMH - 1 : y0);
    int y1i = y0 + 1;  y1i = y1i > IMH - 1 ? IMH - 1 : y1i;
    int x0 = (int)x0f; x0 = x0 < 0 ? 0 : (x0 > IMW - 1 ? IMW - 1 : x0);
    int x1i = x0 + 1;  x1i = x1i > IMW - 1 ? IMW - 1 : x1i;
    float m00 = img[((size_t)y0 * IMW + x0) * MAXGT];
    float m01 = img[((size_t)y0 * IMW + x1i) * MAXGT];
    float m10 = img[((size_t)y1i * IMW + x0) * MAXGT];
    float m11 = img[((size_t)y1i * IMW + x1i) * MAXGT];
    float v = m00 * (1.0f - fy) * (1.0f - fx)
            + m01 * (1.0f - fy) * fx
            + m10 * fy * (1.0f - fx)
            + m11 * fy * fx;
    mo[p] = rintf(v);  // jnp.round: half-to-even; * pos_valid(==1) implicit
  }
}

extern "C" void kernel_launch(void* const* d_in, const int* in_sizes, int n_in,
                              void* d_out, int out_size, void* d_ws,
                              size_t ws_size, hipStream_t stream) {
  const float* proposals = (const float*)d_in[0];
  const int* gt_class = (const int*)d_in[1];
  const float* gt_boxes = (const float*)d_in[2];
  const float* gmasks = (const float*)d_in[3];
  const float* std_dev = (const float*)d_in[4];
  float* out = (float*)d_out;

  // ws layout: pos_s [NB*NPROP f32] | neg_s [NB*NPROP f32] |
  //            slots [NB*NUMPOS*2 i32] | arg [NB*NPROP u8]   (~300 KB total)
  float* ws_pos_s = (float*)d_ws;
  float* ws_neg_s = ws_pos_s + NB * NPROP;
  int* ws_slots = (int*)(ws_neg_s + NB * NPROP);
  unsigned char* ws_arg = (unsigned char*)(ws_slots + NB * NUMPOS * 2);

  dim3 g1((NPROP + BLK - 1) / BLK, NB);
  dtl_score_kernel<<<g1, BLK, 0, stream>>>(proposals, gt_class, gt_boxes,
                                           ws_pos_s, ws_neg_s, ws_arg);
  dtl_topk_kernel<<<NB * 2, BLK, 0, stream>>>(proposals, gt_class, gt_boxes,
                                              std_dev, ws_pos_s, ws_neg_s,
                                              ws_arg, out, ws_slots);
  dtl_mask_kernel<<<NB * NROIS, 256, 0, stream>>>(proposals, gmasks, ws_slots,
                                                  out);
}